// Round 2
// baseline (1188.635 us; speedup 1.0000x reference)
//
#include <hip/hip_runtime.h>

typedef float  f32x4 __attribute__((ext_vector_type(4)));
typedef _Float16 half8 __attribute__((ext_vector_type(8)));
typedef _Float16 half4 __attribute__((ext_vector_type(4)));

#define BN_EPS 1e-5f
#define NGRAPH 64

// ---------------------------------------------------------------- weights prep
struct PrepArgs {
    const float* src[8];
    _Float16*    dst[8];
    int          K[8];
};

// transpose [K][256] f32 -> [256][K] fp16, dst-major (coalesced writes)
__global__ void prep_weights(PrepArgs a) {
    int m = blockIdx.y;
    int K = a.K[m];
    int total = K << 8;
    int idx = blockIdx.x * blockDim.x + threadIdx.x;
    if (idx >= total) return;
    int n = idx / K;
    int k = idx - n * K;
    a.dst[m][idx] = (_Float16)a.src[m][(size_t)k * 256 + n];
}

// ---------------------------------------------------------------- CSR build
__global__ void edge_count(const int* __restrict__ ei, int* __restrict__ cnt, int E) {
    int e = blockIdx.x * blockDim.x + threadIdx.x;
    if (e < E) atomicAdd(&cnt[ei[E + e]], 1);
}

__global__ void scan_p1(const int* __restrict__ cnt, int* __restrict__ part, int N) {
    __shared__ int lds[256];
    int idx = blockIdx.x * 256 + threadIdx.x;
    lds[threadIdx.x] = (idx < N) ? cnt[idx] : 0;
    __syncthreads();
    for (int d = 128; d > 0; d >>= 1) {
        if (threadIdx.x < d) lds[threadIdx.x] += lds[threadIdx.x + d];
        __syncthreads();
    }
    if (threadIdx.x == 0) part[blockIdx.x] = lds[0];
}

__global__ void scan_p2(int* __restrict__ part, int* __restrict__ off, int N, int nb) {
    __shared__ int lds[256];
    int t = threadIdx.x;
    int v = (t < nb) ? part[t] : 0;
    lds[t] = v;
    __syncthreads();
    for (int d = 1; d < 256; d <<= 1) {
        int a = (t >= d) ? lds[t - d] : 0;
        __syncthreads();
        lds[t] += a;
        __syncthreads();
    }
    if (t < nb) part[t] = lds[t] - v;       // exclusive
    if (t == nb - 1) off[N] = lds[t];       // total = E
}

__global__ void scan_p3(const int* __restrict__ cnt, const int* __restrict__ part,
                        int* __restrict__ off, int* __restrict__ cursor, int N) {
    __shared__ int lds[256];
    int t = threadIdx.x;
    int idx = blockIdx.x * 256 + t;
    int v = (idx < N) ? cnt[idx] : 0;
    lds[t] = v;
    __syncthreads();
    for (int d = 1; d < 256; d <<= 1) {
        int a = (t >= d) ? lds[t - d] : 0;
        __syncthreads();
        lds[t] += a;
        __syncthreads();
    }
    if (idx < N) {
        int o = part[blockIdx.x] + lds[t] - v;
        off[idx] = o;
        cursor[idx] = o;
    }
}

__global__ void edge_fill(const int* __restrict__ ei, int* __restrict__ cursor,
                          int* __restrict__ csr_src, int E) {
    int e = blockIdx.x * blockDim.x + threadIdx.x;
    if (e >= E) return;
    int d = ei[E + e];
    int p = atomicAdd(&cursor[d], 1);
    csr_src[p] = ei[e];
}

// ---------------------------------------------------------------- gather (agg + self)
// one wave per node; two edges in flight (half-wave each); 16B per lane.
__global__ void gather_f32(const float* __restrict__ x, const int* __restrict__ off,
                           const int* __restrict__ srcs, _Float16* __restrict__ out, int N) {
    int wid = (blockIdx.x << 2) + (threadIdx.x >> 6);
    if (wid >= N) return;
    int lane = threadIdx.x & 63;
    int half = lane >> 5;
    int fb = (lane & 31) << 2;              // 4 f32 per lane, 128 features
    float acc[4] = {0.f, 0.f, 0.f, 0.f};
    int beg = off[wid], end = off[wid + 1];
    int e = beg + half;
    for (; e + 2 < end; e += 4) {
        int s0 = srcs[e], s1 = srcs[e + 2];
        f32x4 v0 = *(const f32x4*)(x + (size_t)s0 * 128 + fb);
        f32x4 v1 = *(const f32x4*)(x + (size_t)s1 * 128 + fb);
#pragma unroll
        for (int k = 0; k < 4; ++k) acc[k] += v0[k] + v1[k];
    }
    if (e < end) {
        int s0 = srcs[e];
        f32x4 v0 = *(const f32x4*)(x + (size_t)s0 * 128 + fb);
#pragma unroll
        for (int k = 0; k < 4; ++k) acc[k] += v0[k];
    }
    if (half == 0) {                         // self term
        f32x4 v = *(const f32x4*)(x + (size_t)wid * 128 + fb);
#pragma unroll
        for (int k = 0; k < 4; ++k) acc[k] += v[k];
    }
#pragma unroll
    for (int k = 0; k < 4; ++k) acc[k] += __shfl_xor(acc[k], 32);
    if (half == 0) {
        half4 o;
#pragma unroll
        for (int k = 0; k < 4; ++k) o[k] = (_Float16)acc[k];
        *(half4*)(out + (size_t)wid * 128 + fb) = o;
    }
}

__global__ void gather_f16(const _Float16* __restrict__ h, const int* __restrict__ off,
                           const int* __restrict__ srcs, _Float16* __restrict__ out, int N) {
    int wid = (blockIdx.x << 2) + (threadIdx.x >> 6);
    if (wid >= N) return;
    int lane = threadIdx.x & 63;
    int half = lane >> 5;
    int fb = (lane & 31) << 3;              // 8 fp16 per lane, 256 features
    float acc[8] = {0.f, 0.f, 0.f, 0.f, 0.f, 0.f, 0.f, 0.f};
    int beg = off[wid], end = off[wid + 1];
    int e = beg + half;
    for (; e + 2 < end; e += 4) {
        int s0 = srcs[e], s1 = srcs[e + 2];
        half8 v0 = *(const half8*)(h + (size_t)s0 * 256 + fb);
        half8 v1 = *(const half8*)(h + (size_t)s1 * 256 + fb);
#pragma unroll
        for (int k = 0; k < 8; ++k) acc[k] += (float)v0[k] + (float)v1[k];
    }
    if (e < end) {
        int s0 = srcs[e];
        half8 v0 = *(const half8*)(h + (size_t)s0 * 256 + fb);
#pragma unroll
        for (int k = 0; k < 8; ++k) acc[k] += (float)v0[k];
    }
    if (half == 0) {                         // self term
        half8 v = *(const half8*)(h + (size_t)wid * 256 + fb);
#pragma unroll
        for (int k = 0; k < 8; ++k) acc[k] += (float)v[k];
    }
#pragma unroll
    for (int k = 0; k < 8; ++k) acc[k] += __shfl_xor(acc[k], 32);
    if (half == 0) {
        half8 o;
#pragma unroll
        for (int k = 0; k < 8; ++k) o[k] = (_Float16)acc[k];
        *(half8*)(out + (size_t)wid * 256 + fb) = o;
    }
}

// ---------------------------------------------------------------- GEMM (fp16 MFMA)
// C[M,256] = A[M,K] @ W[K,256] (+bias). BT = W^T [256][K] fp16.
// BM=128 (8 waves x 16 rows), BN=128 (blockIdx.y half), T2 XOR-swizzled LDS.
// WITH_STATS: write f32 Z and accumulate per-column sum/sumsq (BN statistics).
template <int K, int WITH_STATS>
__global__ __launch_bounds__(512, 2) void gemm_kernel(
    const _Float16* __restrict__ A, const _Float16* __restrict__ BT,
    const float* __restrict__ bias, _Float16* __restrict__ Y,
    float* __restrict__ Z, float* __restrict__ stats, int M) {
    extern __shared__ _Float16 blds[];      // [128][K], k-chunks XOR-swizzled by row
    const int tid = threadIdx.x;
    const int colbase = blockIdx.y * 128;
    {
        int row = tid >> 2;                  // 0..127
        int q = tid & 3;
        int kq = q * (K / 4);
        const _Float16* src = BT + (size_t)(colbase + row) * K + kq;
        _Float16* dst = blds + row * K;
        int sw = (row & 7) << 3;
#pragma unroll
        for (int c = 0; c < K / 4; c += 8)
            *(half8*)(dst + ((kq + c) ^ sw)) = *(const half8*)(src + c);
    }
    __syncthreads();

    const int lane = tid & 63;
    const int wave = tid >> 6;
    const int i = lane & 15;
    const int g = lane >> 4;
    const int rowbase = blockIdx.x * 128 + wave * 16;
    const int arow = min(rowbase + i, M - 1);

    half8 afrag[K / 32];
#pragma unroll
    for (int s = 0; s < K / 32; ++s)
        afrag[s] = *(const half8*)(A + (size_t)arow * K + s * 32 + g * 8);

    f32x4 acc[8];
#pragma unroll
    for (int t = 0; t < 8; ++t) acc[t] = (f32x4){0.f, 0.f, 0.f, 0.f};

    const int sw = (i & 7) << 3;
#pragma unroll
    for (int s = 0; s < K / 32; ++s) {
#pragma unroll
        for (int t = 0; t < 8; ++t) {
            half8 b = *(const half8*)(blds + (t * 16 + i) * K + ((s * 32 + g * 8) ^ sw));
            acc[t] = __builtin_amdgcn_mfma_f32_16x16x32_f16(afrag[s], b, acc[t], 0, 0, 0);
        }
    }

    const int rg = g * 4;
#pragma unroll
    for (int t = 0; t < 8; ++t) {
        int c = colbase + t * 16 + i;
        float bv = bias[c];
        if (WITH_STATS == 0) {
#pragma unroll
            for (int j = 0; j < 4; ++j) {
                int r = rowbase + rg + j;
                if (r < M) Y[(size_t)r * 256 + c] = (_Float16)fmaxf(acc[t][j] + bv, 0.f);
            }
        } else {
            float s1 = 0.f, s2 = 0.f;
#pragma unroll
            for (int j = 0; j < 4; ++j) {
                int r = rowbase + rg + j;
                if (r < M) {
                    float v = acc[t][j] + bv;
                    Z[(size_t)r * 256 + c] = v;
                    s1 += v;
                    s2 += v * v;
                }
            }
            s1 += __shfl_xor(s1, 16); s1 += __shfl_xor(s1, 32);
            s2 += __shfl_xor(s2, 16); s2 += __shfl_xor(s2, 32);
            if (g == 0) {
                atomicAdd(&stats[c], s1);
                atomicAdd(&stats[256 + c], s2);
            }
        }
    }
}

// ---------------------------------------------------------------- BN + ReLU + fp16 cast
__global__ void norm_kernel(const float* __restrict__ Zin, const float* __restrict__ stats,
                            const float* __restrict__ gam, const float* __restrict__ bet,
                            _Float16* __restrict__ hout, int total, float invN) {
    int base = (blockIdx.x * blockDim.x + threadIdx.x) << 2;
    if (base >= total) return;
    int c = base & 255;
    f32x4 v = *(const f32x4*)(Zin + base);
    half4 o;
#pragma unroll
    for (int j = 0; j < 4; ++j) {
        float mu = stats[c + j] * invN;
        float var = stats[256 + c + j] * invN - mu * mu;
        float s = gam[c + j] * rsqrtf(var + BN_EPS);
        float t = bet[c + j] - mu * s;
        o[j] = (_Float16)fmaxf(v[j] * s + t, 0.f);
    }
    *(half4*)(hout + base) = o;
}

// ---------------------------------------------------------------- global mean pool
__global__ void pool_kernel(const _Float16* __restrict__ h, const int* __restrict__ batch,
                            float* __restrict__ out, int N) {
    __shared__ float lds[1024];
    int gph = blockIdx.x;
    int f = threadIdx.x & 255;
    int rq = threadIdx.x >> 8;
    int lo = 0, hi = N;
    while (lo < hi) { int m = (lo + hi) >> 1; if (batch[m] < gph) lo = m + 1; else hi = m; }
    int a = lo, b = N;
    while (a < b) { int m = (a + b) >> 1; if (batch[m] <= gph) a = m + 1; else b = m; }
    int cnt = a - lo;
    float s = 0.f;
    for (int r = lo + rq; r < a; r += 4) s += (float)h[(size_t)r * 256 + f];
    lds[threadIdx.x] = s;
    __syncthreads();
    if (rq == 0) {
        s = lds[f] + lds[f + 256] + lds[f + 512] + lds[f + 768];
        out[gph * 256 + f] = s / (float)(cnt > 0 ? cnt : 1);
    }
}

// ---------------------------------------------------------------- launch
extern "C" void kernel_launch(void* const* d_in, const int* in_sizes, int n_in,
                              void* d_out, int out_size, void* d_ws, size_t ws_size,
                              hipStream_t stream) {
    const float* x    = (const float*)d_in[0];
    const int*   ei   = (const int*)d_in[1];
    const int*   batch= (const int*)d_in[2];
    const float* w1_0 = (const float*)d_in[3];
    const float* b1_0 = (const float*)d_in[4];
    const float* w2_0 = (const float*)d_in[5];
    const float* b2_0 = (const float*)d_in[6];
    const float* g_0  = (const float*)d_in[7];
    const float* be_0 = (const float*)d_in[8];
    const float* w1_r = (const float*)d_in[9];
    const float* b1_r = (const float*)d_in[10];
    const float* w2_r = (const float*)d_in[11];
    const float* b2_r = (const float*)d_in[12];
    const float* g_r  = (const float*)d_in[13];
    const float* be_r = (const float*)d_in[14];

    const int N = in_sizes[0] / 128;   // 50000
    const int E = in_sizes[1] / 2;     // 800000

    // workspace carve (256B aligned)
    char* p = (char*)d_ws;
    auto alloc = [&](size_t bytes) { char* r = p; p += (bytes + 255) & ~(size_t)255; return r; };
    float*    stats   = (float*)alloc(4 * 512 * sizeof(float));
    int*      part    = (int*)alloc(256 * sizeof(int));
    int*      off     = (int*)alloc((size_t)(N + 1) * sizeof(int));
    int*      cnt     = (int*)alloc((size_t)N * sizeof(int));
    int*      cursor  = (int*)alloc((size_t)N * sizeof(int));
    int*      csr_src = (int*)alloc((size_t)E * sizeof(int));
    _Float16* wT      = (_Float16*)alloc((size_t)491520 * sizeof(_Float16));
    _Float16* zin     = (_Float16*)alloc((size_t)N * 256 * sizeof(_Float16));
    _Float16* y       = (_Float16*)alloc((size_t)N * 256 * sizeof(_Float16));
    _Float16* h       = (_Float16*)alloc((size_t)N * 256 * sizeof(_Float16));
    float*    z       = (float*)alloc((size_t)N * 256 * sizeof(float));

    hipMemsetAsync(stats, 0, 4 * 512 * sizeof(float), stream);
    hipMemsetAsync(cnt, 0, (size_t)N * sizeof(int), stream);

    // transpose all weights to fp16 [256][K]
    PrepArgs pa;
    pa.src[0] = w1_0;  pa.dst[0] = wT;           pa.K[0] = 128;
    pa.src[1] = w2_0;  pa.dst[1] = wT + 32768;   pa.K[1] = 256;
    for (int i = 0; i < 3; ++i) {
        pa.src[2 + i] = w1_r + (size_t)i * 65536; pa.dst[2 + i] = wT + 98304 + (size_t)i * 65536; pa.K[2 + i] = 256;
        pa.src[5 + i] = w2_r + (size_t)i * 65536; pa.dst[5 + i] = wT + 294912 + (size_t)i * 65536; pa.K[5 + i] = 256;
    }
    prep_weights<<<dim3(256, 8), 256, 0, stream>>>(pa);

    const int eb = (E + 255) / 256;
    const int nb = (N + 255) / 256;
    edge_count<<<eb, 256, 0, stream>>>(ei, cnt, E);
    scan_p1<<<nb, 256, 0, stream>>>(cnt, part, N);
    scan_p2<<<1, 256, 0, stream>>>(part, off, N, nb);
    scan_p3<<<nb, 256, 0, stream>>>(cnt, part, off, cursor, N);
    edge_fill<<<eb, 256, 0, stream>>>(ei, cursor, csr_src, E);

    const int gwb   = (N + 3) / 4;               // gather blocks (4 waves each)
    const dim3 gemmg((N + 127) / 128, 2);
    const int nrmb  = ((N * 256 / 4) + 255) / 256;
    const int total = N * 256;
    const float invN = 1.0f / (float)N;

    // ---- layer 0 (K=128 input)
    gather_f32<<<gwb, 256, 0, stream>>>(x, off, csr_src, zin, N);
    gemm_kernel<128, 0><<<gemmg, 512, 128 * 128 * 2, stream>>>(zin, wT, b1_0, y, nullptr, nullptr, N);
    gemm_kernel<256, 1><<<gemmg, 512, 128 * 256 * 2, stream>>>(y, wT + 32768, b2_0, nullptr, z, stats, N);
    norm_kernel<<<nrmb, 256, 0, stream>>>(z, stats, g_0, be_0, h, total, invN);

    // ---- layers 1..3
    for (int i = 0; i < 3; ++i) {
        gather_f16<<<gwb, 256, 0, stream>>>(h, off, csr_src, zin, N);
        gemm_kernel<256, 0><<<gemmg, 512, 128 * 256 * 2, stream>>>(
            zin, wT + 98304 + (size_t)i * 65536, b1_r + i * 256, y, nullptr, nullptr, N);
        gemm_kernel<256, 1><<<gemmg, 512, 128 * 256 * 2, stream>>>(
            y, wT + 294912 + (size_t)i * 65536, b2_r + i * 256, nullptr, z, stats + (i + 1) * 512, N);
        norm_kernel<<<nrmb, 256, 0, stream>>>(z, stats + (i + 1) * 512, g_r + i * 256, be_r + i * 256, h, total, invN);
    }

    pool_kernel<<<NGRAPH, 1024, 0, stream>>>(h, batch, (float*)d_out, N);
}

// Round 3
// 700.667 us; speedup vs baseline: 1.6964x; 1.6964x over previous
//
#include <hip/hip_runtime.h>

typedef float  f32x4 __attribute__((ext_vector_type(4)));
typedef _Float16 half8 __attribute__((ext_vector_type(8)));
typedef _Float16 half4 __attribute__((ext_vector_type(4)));

#define BN_EPS 1e-5f
#define NGRAPH 64

// ---------------------------------------------------------------- weights prep
struct PrepArgs {
    const float* src[8];
    _Float16*    dst[8];
    int          K[8];
};

// transpose [K][256] f32 -> [256][K] fp16, dst-major (coalesced writes)
__global__ void prep_weights(PrepArgs a) {
    int m = blockIdx.y;
    int K = a.K[m];
    int total = K << 8;
    int idx = blockIdx.x * blockDim.x + threadIdx.x;
    if (idx >= total) return;
    int n = idx / K;
    int k = idx - n * K;
    a.dst[m][idx] = (_Float16)a.src[m][(size_t)k * 256 + n];
}

// ---------------------------------------------------------------- CSR build
__global__ void edge_count(const int* __restrict__ ei, int* __restrict__ cnt, int E) {
    int e = blockIdx.x * blockDim.x + threadIdx.x;
    if (e < E) atomicAdd(&cnt[ei[E + e]], 1);
}

__global__ void scan_p1(const int* __restrict__ cnt, int* __restrict__ part, int N) {
    __shared__ int lds[256];
    int idx = blockIdx.x * 256 + threadIdx.x;
    lds[threadIdx.x] = (idx < N) ? cnt[idx] : 0;
    __syncthreads();
    for (int d = 128; d > 0; d >>= 1) {
        if (threadIdx.x < d) lds[threadIdx.x] += lds[threadIdx.x + d];
        __syncthreads();
    }
    if (threadIdx.x == 0) part[blockIdx.x] = lds[0];
}

__global__ void scan_p2(int* __restrict__ part, int* __restrict__ off, int N, int nb) {
    __shared__ int lds[256];
    int t = threadIdx.x;
    int v = (t < nb) ? part[t] : 0;
    lds[t] = v;
    __syncthreads();
    for (int d = 1; d < 256; d <<= 1) {
        int a = (t >= d) ? lds[t - d] : 0;
        __syncthreads();
        lds[t] += a;
        __syncthreads();
    }
    if (t < nb) part[t] = lds[t] - v;       // exclusive
    if (t == nb - 1) off[N] = lds[t];       // total = E
}

__global__ void scan_p3(const int* __restrict__ cnt, const int* __restrict__ part,
                        int* __restrict__ off, int* __restrict__ cursor, int N) {
    __shared__ int lds[256];
    int t = threadIdx.x;
    int idx = blockIdx.x * 256 + t;
    int v = (idx < N) ? cnt[idx] : 0;
    lds[t] = v;
    __syncthreads();
    for (int d = 1; d < 256; d <<= 1) {
        int a = (t >= d) ? lds[t - d] : 0;
        __syncthreads();
        lds[t] += a;
        __syncthreads();
    }
    if (idx < N) {
        int o = part[blockIdx.x] + lds[t] - v;
        off[idx] = o;
        cursor[idx] = o;
    }
}

__global__ void edge_fill(const int* __restrict__ ei, int* __restrict__ cursor,
                          int* __restrict__ csr_src, int E) {
    int e = blockIdx.x * blockDim.x + threadIdx.x;
    if (e >= E) return;
    int d = ei[E + e];
    int p = atomicAdd(&cursor[d], 1);
    csr_src[p] = ei[e];
}

// ---------------------------------------------------------------- gather (agg + self)
// one wave per node; two edges in flight (half-wave each); 16B per lane.
__global__ void gather_f32(const float* __restrict__ x, const int* __restrict__ off,
                           const int* __restrict__ srcs, _Float16* __restrict__ out, int N) {
    int wid = (blockIdx.x << 2) + (threadIdx.x >> 6);
    if (wid >= N) return;
    int lane = threadIdx.x & 63;
    int half = lane >> 5;
    int fb = (lane & 31) << 2;              // 4 f32 per lane, 128 features
    float acc[4] = {0.f, 0.f, 0.f, 0.f};
    int beg = off[wid], end = off[wid + 1];
    int e = beg + half;
    for (; e + 2 < end; e += 4) {
        int s0 = srcs[e], s1 = srcs[e + 2];
        f32x4 v0 = *(const f32x4*)(x + (size_t)s0 * 128 + fb);
        f32x4 v1 = *(const f32x4*)(x + (size_t)s1 * 128 + fb);
#pragma unroll
        for (int k = 0; k < 4; ++k) acc[k] += v0[k] + v1[k];
    }
    if (e < end) {
        int s0 = srcs[e];
        f32x4 v0 = *(const f32x4*)(x + (size_t)s0 * 128 + fb);
#pragma unroll
        for (int k = 0; k < 4; ++k) acc[k] += v0[k];
    }
    if (half == 0) {                         // self term
        f32x4 v = *(const f32x4*)(x + (size_t)wid * 128 + fb);
#pragma unroll
        for (int k = 0; k < 4; ++k) acc[k] += v[k];
    }
#pragma unroll
    for (int k = 0; k < 4; ++k) acc[k] += __shfl_xor(acc[k], 32);
    if (half == 0) {
        half4 o;
#pragma unroll
        for (int k = 0; k < 4; ++k) o[k] = (_Float16)acc[k];
        *(half4*)(out + (size_t)wid * 128 + fb) = o;
    }
}

__global__ void gather_f16(const _Float16* __restrict__ h, const int* __restrict__ off,
                           const int* __restrict__ srcs, _Float16* __restrict__ out, int N) {
    int wid = (blockIdx.x << 2) + (threadIdx.x >> 6);
    if (wid >= N) return;
    int lane = threadIdx.x & 63;
    int half = lane >> 5;
    int fb = (lane & 31) << 3;              // 8 fp16 per lane, 256 features
    float acc[8] = {0.f, 0.f, 0.f, 0.f, 0.f, 0.f, 0.f, 0.f};
    int beg = off[wid], end = off[wid + 1];
    int e = beg + half;
    for (; e + 2 < end; e += 4) {
        int s0 = srcs[e], s1 = srcs[e + 2];
        half8 v0 = *(const half8*)(h + (size_t)s0 * 256 + fb);
        half8 v1 = *(const half8*)(h + (size_t)s1 * 256 + fb);
#pragma unroll
        for (int k = 0; k < 8; ++k) acc[k] += (float)v0[k] + (float)v1[k];
    }
    if (e < end) {
        int s0 = srcs[e];
        half8 v0 = *(const half8*)(h + (size_t)s0 * 256 + fb);
#pragma unroll
        for (int k = 0; k < 8; ++k) acc[k] += (float)v0[k];
    }
    if (half == 0) {                         // self term
        half8 v = *(const half8*)(h + (size_t)wid * 256 + fb);
#pragma unroll
        for (int k = 0; k < 8; ++k) acc[k] += (float)v[k];
    }
#pragma unroll
    for (int k = 0; k < 8; ++k) acc[k] += __shfl_xor(acc[k], 32);
    if (half == 0) {
        half8 o;
#pragma unroll
        for (int k = 0; k < 8; ++k) o[k] = (_Float16)acc[k];
        *(half8*)(out + (size_t)wid * 256 + fb) = o;
    }
}

// ---------------------------------------------------------------- GEMM (fp16 MFMA)
// C[M,256] = A[M,K] @ W[K,256] (+bias). BT = W^T [256][K] fp16.
// BM=128 (8 waves x 16 rows), BN=128 (blockIdx.y half), T2 XOR-swizzled LDS.
// WITH_STATS: write fp16 Z (pre-norm) and accumulate per-column sum/sumsq
// block-reduced in LDS -> ONE atomicAdd per column per block (391 per address,
// vs 3128 per-wave before: the round-2 serialization bottleneck).
template <int K, int WITH_STATS>
__global__ __launch_bounds__(512, 2) void gemm_kernel(
    const _Float16* __restrict__ A, const _Float16* __restrict__ BT,
    const float* __restrict__ bias, _Float16* __restrict__ Y,
    _Float16* __restrict__ Z, float* __restrict__ stats, int M) {
    extern __shared__ _Float16 blds[];      // [128][K], k-chunks XOR-swizzled by row
    const int tid = threadIdx.x;
    const int colbase = blockIdx.y * 128;
    {
        int row = tid >> 2;                  // 0..127
        int q = tid & 3;
        int kq = q * (K / 4);
        const _Float16* src = BT + (size_t)(colbase + row) * K + kq;
        _Float16* dst = blds + row * K;
        int sw = (row & 7) << 3;
#pragma unroll
        for (int c = 0; c < K / 4; c += 8)
            *(half8*)(dst + ((kq + c) ^ sw)) = *(const half8*)(src + c);
    }
    __syncthreads();

    const int lane = tid & 63;
    const int wave = tid >> 6;
    const int i = lane & 15;
    const int g = lane >> 4;
    const int rowbase = blockIdx.x * 128 + wave * 16;
    const int arow = min(rowbase + i, M - 1);

    half8 afrag[K / 32];
#pragma unroll
    for (int s = 0; s < K / 32; ++s)
        afrag[s] = *(const half8*)(A + (size_t)arow * K + s * 32 + g * 8);

    f32x4 acc[8];
#pragma unroll
    for (int t = 0; t < 8; ++t) acc[t] = (f32x4){0.f, 0.f, 0.f, 0.f};

    const int sw = (i & 7) << 3;
#pragma unroll
    for (int s = 0; s < K / 32; ++s) {
#pragma unroll
        for (int t = 0; t < 8; ++t) {
            half8 b = *(const half8*)(blds + (t * 16 + i) * K + ((s * 32 + g * 8) ^ sw));
            acc[t] = __builtin_amdgcn_mfma_f32_16x16x32_f16(afrag[s], b, acc[t], 0, 0, 0);
        }
    }

    const int rg = g * 4;
    if (WITH_STATS == 0) {
#pragma unroll
        for (int t = 0; t < 8; ++t) {
            int c = colbase + t * 16 + i;
            float bv = bias[c];
#pragma unroll
            for (int j = 0; j < 4; ++j) {
                int r = rowbase + rg + j;
                if (r < M) Y[(size_t)r * 256 + c] = (_Float16)fmaxf(acc[t][j] + bv, 0.f);
            }
        }
    } else {
        float* sred = (float*)blds;          // reuse weight LDS: [2][8 waves][128 cols]
        __syncthreads();                     // everyone done reading blds
#pragma unroll
        for (int t = 0; t < 8; ++t) {
            int c = colbase + t * 16 + i;
            float bv = bias[c];
            float s1 = 0.f, s2 = 0.f;
#pragma unroll
            for (int j = 0; j < 4; ++j) {
                int r = rowbase + rg + j;
                if (r < M) {
                    float v = acc[t][j] + bv;
                    Z[(size_t)r * 256 + c] = (_Float16)v;
                    s1 += v;
                    s2 += v * v;
                }
            }
            s1 += __shfl_xor(s1, 16); s1 += __shfl_xor(s1, 32);
            s2 += __shfl_xor(s2, 16); s2 += __shfl_xor(s2, 32);
            if (g == 0) {
                sred[wave * 128 + t * 16 + i] = s1;
                sred[1024 + wave * 128 + t * 16 + i] = s2;
            }
        }
        __syncthreads();
        if (tid < 256) {                     // one atomic per column per block
            int which = tid >> 7;            // 0: sum, 1: sumsq
            int c = tid & 127;
            float s = 0.f;
#pragma unroll
            for (int w = 0; w < 8; ++w) s += sred[which * 1024 + w * 128 + c];
            atomicAdd(&stats[which * 256 + colbase + c], s);
        }
    }
}

// ---------------------------------------------------------------- BN + ReLU
__global__ void norm_kernel(const _Float16* __restrict__ Zin, const float* __restrict__ stats,
                            const float* __restrict__ gam, const float* __restrict__ bet,
                            _Float16* __restrict__ hout, int total, float invN) {
    int base = (blockIdx.x * blockDim.x + threadIdx.x) << 3;
    if (base >= total) return;
    int c = base & 255;
    half8 v = *(const half8*)(Zin + base);
    half8 o;
#pragma unroll
    for (int j = 0; j < 8; ++j) {
        float mu = stats[c + j] * invN;
        float var = stats[256 + c + j] * invN - mu * mu;
        float s = gam[c + j] * rsqrtf(var + BN_EPS);
        float t = bet[c + j] - mu * s;
        o[j] = (_Float16)fmaxf((float)v[j] * s + t, 0.f);
    }
    *(half8*)(hout + base) = o;
}

// ---------------------------------------------------------------- global mean pool
__global__ void pool_kernel(const _Float16* __restrict__ h, const int* __restrict__ batch,
                            float* __restrict__ out, int N) {
    __shared__ float lds[1024];
    int gph = blockIdx.x;
    int f = threadIdx.x & 255;
    int rq = threadIdx.x >> 8;
    int lo = 0, hi = N;
    while (lo < hi) { int m = (lo + hi) >> 1; if (batch[m] < gph) lo = m + 1; else hi = m; }
    int a = lo, b = N;
    while (a < b) { int m = (a + b) >> 1; if (batch[m] <= gph) a = m + 1; else b = m; }
    int cnt = a - lo;
    float s = 0.f;
    for (int r = lo + rq; r < a; r += 4) s += (float)h[(size_t)r * 256 + f];
    lds[threadIdx.x] = s;
    __syncthreads();
    if (rq == 0) {
        s = lds[f] + lds[f + 256] + lds[f + 512] + lds[f + 768];
        out[gph * 256 + f] = s / (float)(cnt > 0 ? cnt : 1);
    }
}

// ---------------------------------------------------------------- launch
extern "C" void kernel_launch(void* const* d_in, const int* in_sizes, int n_in,
                              void* d_out, int out_size, void* d_ws, size_t ws_size,
                              hipStream_t stream) {
    const float* x    = (const float*)d_in[0];
    const int*   ei   = (const int*)d_in[1];
    const int*   batch= (const int*)d_in[2];
    const float* w1_0 = (const float*)d_in[3];
    const float* b1_0 = (const float*)d_in[4];
    const float* w2_0 = (const float*)d_in[5];
    const float* b2_0 = (const float*)d_in[6];
    const float* g_0  = (const float*)d_in[7];
    const float* be_0 = (const float*)d_in[8];
    const float* w1_r = (const float*)d_in[9];
    const float* b1_r = (const float*)d_in[10];
    const float* w2_r = (const float*)d_in[11];
    const float* b2_r = (const float*)d_in[12];
    const float* g_r  = (const float*)d_in[13];
    const float* be_r = (const float*)d_in[14];

    const int N = in_sizes[0] / 128;   // 50000
    const int E = in_sizes[1] / 2;     // 800000

    // workspace carve (256B aligned)
    char* p = (char*)d_ws;
    auto alloc = [&](size_t bytes) { char* r = p; p += (bytes + 255) & ~(size_t)255; return r; };
    float*    stats   = (float*)alloc(4 * 512 * sizeof(float));
    int*      part    = (int*)alloc(256 * sizeof(int));
    int*      off     = (int*)alloc((size_t)(N + 1) * sizeof(int));
    int*      cnt     = (int*)alloc((size_t)N * sizeof(int));
    int*      cursor  = (int*)alloc((size_t)N * sizeof(int));
    int*      csr_src = (int*)alloc((size_t)E * sizeof(int));
    _Float16* wT      = (_Float16*)alloc((size_t)491520 * sizeof(_Float16));
    _Float16* zin     = (_Float16*)alloc((size_t)N * 256 * sizeof(_Float16));
    _Float16* y       = (_Float16*)alloc((size_t)N * 256 * sizeof(_Float16));
    _Float16* h       = (_Float16*)alloc((size_t)N * 256 * sizeof(_Float16));
    _Float16* z       = (_Float16*)alloc((size_t)N * 256 * sizeof(_Float16));

    hipMemsetAsync(stats, 0, 4 * 512 * sizeof(float), stream);
    hipMemsetAsync(cnt, 0, (size_t)N * sizeof(int), stream);

    // transpose all weights to fp16 [256][K]
    PrepArgs pa;
    pa.src[0] = w1_0;  pa.dst[0] = wT;           pa.K[0] = 128;
    pa.src[1] = w2_0;  pa.dst[1] = wT + 32768;   pa.K[1] = 256;
    for (int i = 0; i < 3; ++i) {
        pa.src[2 + i] = w1_r + (size_t)i * 65536; pa.dst[2 + i] = wT + 98304 + (size_t)i * 65536; pa.K[2 + i] = 256;
        pa.src[5 + i] = w2_r + (size_t)i * 65536; pa.dst[5 + i] = wT + 294912 + (size_t)i * 65536; pa.K[5 + i] = 256;
    }
    prep_weights<<<dim3(256, 8), 256, 0, stream>>>(pa);

    const int eb = (E + 255) / 256;
    const int nb = (N + 255) / 256;
    edge_count<<<eb, 256, 0, stream>>>(ei, cnt, E);
    scan_p1<<<nb, 256, 0, stream>>>(cnt, part, N);
    scan_p2<<<1, 256, 0, stream>>>(part, off, N, nb);
    scan_p3<<<nb, 256, 0, stream>>>(cnt, part, off, cursor, N);
    edge_fill<<<eb, 256, 0, stream>>>(ei, cursor, csr_src, E);

    const int gwb   = (N + 3) / 4;               // gather blocks (4 waves each)
    const dim3 gemmg((N + 127) / 128, 2);
    const int nrmb  = ((N * 256 / 8) + 255) / 256;
    const int total = N * 256;
    const float invN = 1.0f / (float)N;

    // ---- layer 0 (K=128 input)
    gather_f32<<<gwb, 256, 0, stream>>>(x, off, csr_src, zin, N);
    gemm_kernel<128, 0><<<gemmg, 512, 128 * 128 * 2, stream>>>(zin, wT, b1_0, y, nullptr, nullptr, N);
    gemm_kernel<256, 1><<<gemmg, 512, 128 * 256 * 2, stream>>>(y, wT + 32768, b2_0, nullptr, z, stats, N);
    norm_kernel<<<nrmb, 256, 0, stream>>>(z, stats, g_0, be_0, h, total, invN);

    // ---- layers 1..3
    for (int i = 0; i < 3; ++i) {
        gather_f16<<<gwb, 256, 0, stream>>>(h, off, csr_src, zin, N);
        gemm_kernel<256, 0><<<gemmg, 512, 128 * 256 * 2, stream>>>(
            zin, wT + 98304 + (size_t)i * 65536, b1_r + i * 256, y, nullptr, nullptr, N);
        gemm_kernel<256, 1><<<gemmg, 512, 128 * 256 * 2, stream>>>(
            y, wT + 294912 + (size_t)i * 65536, b2_r + i * 256, nullptr, z, stats + (i + 1) * 512, N);
        norm_kernel<<<nrmb, 256, 0, stream>>>(z, stats + (i + 1) * 512, g_r + i * 256, be_r + i * 256, h, total, invN);
    }

    pool_kernel<<<NGRAPH, 1024, 0, stream>>>(h, batch, (float*)d_out, N);
}

// Round 4
// 576.118 us; speedup vs baseline: 2.0632x; 1.2162x over previous
//
#include <hip/hip_runtime.h>

typedef float  f32x4 __attribute__((ext_vector_type(4)));
typedef _Float16 half8 __attribute__((ext_vector_type(8)));
typedef _Float16 half4 __attribute__((ext_vector_type(4)));

#define BN_EPS 1e-5f
#define NGRAPH 64

// ---------------------------------------------------------------- weights prep
struct PrepArgs {
    const float* src[8];
    _Float16*    dst[8];
    int          K[8];
};

// transpose [K][256] f32 -> [256][K] fp16, dst-major (coalesced writes)
__global__ void prep_weights(PrepArgs a) {
    int m = blockIdx.y;
    int K = a.K[m];
    int total = K << 8;
    int idx = blockIdx.x * blockDim.x + threadIdx.x;
    if (idx >= total) return;
    int n = idx / K;
    int k = idx - n * K;
    a.dst[m][idx] = (_Float16)a.src[m][(size_t)k * 256 + n];
}

// ---------------------------------------------------------------- CSR build
// count + rank in one pass: rank[e] = position of edge e within its dst segment.
__global__ void edge_count(const int* __restrict__ ei, int* __restrict__ cnt,
                           int* __restrict__ rank, int E) {
    int e = blockIdx.x * blockDim.x + threadIdx.x;
    if (e < E) rank[e] = atomicAdd(&cnt[ei[E + e]], 1);
}

__global__ void scan_p1(const int* __restrict__ cnt, int* __restrict__ part, int N) {
    __shared__ int lds[256];
    int idx = blockIdx.x * 256 + threadIdx.x;
    lds[threadIdx.x] = (idx < N) ? cnt[idx] : 0;
    __syncthreads();
    for (int d = 128; d > 0; d >>= 1) {
        if (threadIdx.x < d) lds[threadIdx.x] += lds[threadIdx.x + d];
        __syncthreads();
    }
    if (threadIdx.x == 0) part[blockIdx.x] = lds[0];
}

__global__ void scan_p2(int* __restrict__ part, int* __restrict__ off, int N, int nb) {
    __shared__ int lds[256];
    int t = threadIdx.x;
    int v = (t < nb) ? part[t] : 0;
    lds[t] = v;
    __syncthreads();
    for (int d = 1; d < 256; d <<= 1) {
        int a = (t >= d) ? lds[t - d] : 0;
        __syncthreads();
        lds[t] += a;
        __syncthreads();
    }
    if (t < nb) part[t] = lds[t] - v;       // exclusive
    if (t == nb - 1) off[N] = lds[t];       // total = E
}

__global__ void scan_p3(const int* __restrict__ cnt, const int* __restrict__ part,
                        int* __restrict__ off, int N) {
    __shared__ int lds[256];
    int t = threadIdx.x;
    int idx = blockIdx.x * 256 + t;
    int v = (idx < N) ? cnt[idx] : 0;
    lds[t] = v;
    __syncthreads();
    for (int d = 1; d < 256; d <<= 1) {
        int a = (t >= d) ? lds[t - d] : 0;
        __syncthreads();
        lds[t] += a;
        __syncthreads();
    }
    if (idx < N) off[idx] = part[blockIdx.x] + lds[t] - v;
}

// atomic-free fill: slot = off[dst] + rank  (round-3 fix for 52MB atomic writeback)
__global__ void edge_fill(const int* __restrict__ ei, const int* __restrict__ off,
                          const int* __restrict__ rank, int* __restrict__ csr_src, int E) {
    int e = blockIdx.x * blockDim.x + threadIdx.x;
    if (e >= E) return;
    csr_src[off[ei[E + e]] + rank[e]] = ei[e];
}

// ---------------------------------------------------------------- gather (agg + self)
// one wave per node; two edges in flight (half-wave each); 16B per lane.
__global__ void gather_f32(const float* __restrict__ x, const int* __restrict__ off,
                           const int* __restrict__ srcs, _Float16* __restrict__ out, int N) {
    int wid = (blockIdx.x << 2) + (threadIdx.x >> 6);
    if (wid >= N) return;
    int lane = threadIdx.x & 63;
    int half = lane >> 5;
    int fb = (lane & 31) << 2;              // 4 f32 per lane, 128 features
    float acc[4] = {0.f, 0.f, 0.f, 0.f};
    int beg = off[wid], end = off[wid + 1];
    int e = beg + half;
    for (; e + 2 < end; e += 4) {
        int s0 = srcs[e], s1 = srcs[e + 2];
        f32x4 v0 = *(const f32x4*)(x + (size_t)s0 * 128 + fb);
        f32x4 v1 = *(const f32x4*)(x + (size_t)s1 * 128 + fb);
#pragma unroll
        for (int k = 0; k < 4; ++k) acc[k] += v0[k] + v1[k];
    }
    if (e < end) {
        int s0 = srcs[e];
        f32x4 v0 = *(const f32x4*)(x + (size_t)s0 * 128 + fb);
#pragma unroll
        for (int k = 0; k < 4; ++k) acc[k] += v0[k];
    }
    if (half == 0) {                         // self term
        f32x4 v = *(const f32x4*)(x + (size_t)wid * 128 + fb);
#pragma unroll
        for (int k = 0; k < 4; ++k) acc[k] += v[k];
    }
#pragma unroll
    for (int k = 0; k < 4; ++k) acc[k] += __shfl_xor(acc[k], 32);
    if (half == 0) {
        half4 o;
#pragma unroll
        for (int k = 0; k < 4; ++k) o[k] = (_Float16)acc[k];
        *(half4*)(out + (size_t)wid * 128 + fb) = o;
    }
}

// fused: reads PRE-norm z, applies BN affine + ReLU on the fly (h never materialized)
__global__ void gather_fused(const _Float16* __restrict__ z, const int* __restrict__ off,
                             const int* __restrict__ srcs, const float* __restrict__ stats,
                             const float* __restrict__ gam, const float* __restrict__ bet,
                             _Float16* __restrict__ out, int N, float invN) {
    int wid = (blockIdx.x << 2) + (threadIdx.x >> 6);
    if (wid >= N) return;
    int lane = threadIdx.x & 63;
    int half = lane >> 5;
    int fb = (lane & 31) << 3;              // 8 fp16 per lane, 256 features
    float sc[8], tc[8];
#pragma unroll
    for (int k = 0; k < 8; ++k) {
        float mu = stats[fb + k] * invN;
        float var = stats[256 + fb + k] * invN - mu * mu;
        float s = gam[fb + k] * rsqrtf(var + BN_EPS);
        sc[k] = s;
        tc[k] = bet[fb + k] - mu * s;
    }
    float acc[8] = {0.f, 0.f, 0.f, 0.f, 0.f, 0.f, 0.f, 0.f};
    int beg = off[wid], end = off[wid + 1];
    int e = beg + half;
    for (; e + 2 < end; e += 4) {
        int s0 = srcs[e], s1 = srcs[e + 2];
        half8 v0 = *(const half8*)(z + (size_t)s0 * 256 + fb);
        half8 v1 = *(const half8*)(z + (size_t)s1 * 256 + fb);
#pragma unroll
        for (int k = 0; k < 8; ++k)
            acc[k] += fmaxf(fmaf((float)v0[k], sc[k], tc[k]), 0.f)
                    + fmaxf(fmaf((float)v1[k], sc[k], tc[k]), 0.f);
    }
    if (e < end) {
        int s0 = srcs[e];
        half8 v0 = *(const half8*)(z + (size_t)s0 * 256 + fb);
#pragma unroll
        for (int k = 0; k < 8; ++k)
            acc[k] += fmaxf(fmaf((float)v0[k], sc[k], tc[k]), 0.f);
    }
    if (half == 0) {                         // self term
        half8 v = *(const half8*)(z + (size_t)wid * 256 + fb);
#pragma unroll
        for (int k = 0; k < 8; ++k)
            acc[k] += fmaxf(fmaf((float)v[k], sc[k], tc[k]), 0.f);
    }
#pragma unroll
    for (int k = 0; k < 8; ++k) acc[k] += __shfl_xor(acc[k], 32);
    if (half == 0) {
        half8 o;
#pragma unroll
        for (int k = 0; k < 8; ++k) o[k] = (_Float16)acc[k];
        *(half8*)(out + (size_t)wid * 256 + fb) = o;
    }
}

// ---------------------------------------------------------------- GEMM (fp16 MFMA)
// C[M,256] = A[M,K] @ W[K,256] (+bias). BT = W^T [256][K] fp16.
// BM=128 (8 waves x 16 rows), BN=128 (blockIdx.y half), T2 XOR-swizzled LDS.
// WITH_STATS: write fp16 Z (pre-norm) + block-reduced column sum/sumsq, one
// atomicAdd per column per block.
template <int K, int WITH_STATS>
__global__ __launch_bounds__(512, 2) void gemm_kernel(
    const _Float16* __restrict__ A, const _Float16* __restrict__ BT,
    const float* __restrict__ bias, _Float16* __restrict__ Y,
    _Float16* __restrict__ Z, float* __restrict__ stats, int M) {
    extern __shared__ _Float16 blds[];      // [128][K], k-chunks XOR-swizzled by row
    const int tid = threadIdx.x;
    const int colbase = blockIdx.y * 128;
    {
        int row = tid >> 2;                  // 0..127
        int q = tid & 3;
        int kq = q * (K / 4);
        const _Float16* src = BT + (size_t)(colbase + row) * K + kq;
        _Float16* dst = blds + row * K;
        int sw = (row & 7) << 3;
#pragma unroll
        for (int c = 0; c < K / 4; c += 8)
            *(half8*)(dst + ((kq + c) ^ sw)) = *(const half8*)(src + c);
    }
    __syncthreads();

    const int lane = tid & 63;
    const int wave = tid >> 6;
    const int i = lane & 15;
    const int g = lane >> 4;
    const int rowbase = blockIdx.x * 128 + wave * 16;
    const int arow = min(rowbase + i, M - 1);

    half8 afrag[K / 32];
#pragma unroll
    for (int s = 0; s < K / 32; ++s)
        afrag[s] = *(const half8*)(A + (size_t)arow * K + s * 32 + g * 8);

    f32x4 acc[8];
#pragma unroll
    for (int t = 0; t < 8; ++t) acc[t] = (f32x4){0.f, 0.f, 0.f, 0.f};

    const int sw = (i & 7) << 3;
#pragma unroll
    for (int s = 0; s < K / 32; ++s) {
#pragma unroll
        for (int t = 0; t < 8; ++t) {
            half8 b = *(const half8*)(blds + (t * 16 + i) * K + ((s * 32 + g * 8) ^ sw));
            acc[t] = __builtin_amdgcn_mfma_f32_16x16x32_f16(afrag[s], b, acc[t], 0, 0, 0);
        }
    }

    const int rg = g * 4;
    if (WITH_STATS == 0) {
#pragma unroll
        for (int t = 0; t < 8; ++t) {
            int c = colbase + t * 16 + i;
            float bv = bias[c];
#pragma unroll
            for (int j = 0; j < 4; ++j) {
                int r = rowbase + rg + j;
                if (r < M) Y[(size_t)r * 256 + c] = (_Float16)fmaxf(acc[t][j] + bv, 0.f);
            }
        }
    } else {
        float* sred = (float*)blds;          // reuse weight LDS: [2][8 waves][128 cols]
        __syncthreads();                     // everyone done reading blds
#pragma unroll
        for (int t = 0; t < 8; ++t) {
            int c = colbase + t * 16 + i;
            float bv = bias[c];
            float s1 = 0.f, s2 = 0.f;
#pragma unroll
            for (int j = 0; j < 4; ++j) {
                int r = rowbase + rg + j;
                if (r < M) {
                    float v = acc[t][j] + bv;
                    Z[(size_t)r * 256 + c] = (_Float16)v;
                    s1 += v;
                    s2 += v * v;
                }
            }
            s1 += __shfl_xor(s1, 16); s1 += __shfl_xor(s1, 32);
            s2 += __shfl_xor(s2, 16); s2 += __shfl_xor(s2, 32);
            if (g == 0) {
                sred[wave * 128 + t * 16 + i] = s1;
                sred[1024 + wave * 128 + t * 16 + i] = s2;
            }
        }
        __syncthreads();
        if (tid < 256) {                     // one atomic per column per block
            int which = tid >> 7;            // 0: sum, 1: sumsq
            int c = tid & 127;
            float s = 0.f;
#pragma unroll
            for (int w = 0; w < 8; ++w) s += sred[which * 1024 + w * 128 + c];
            atomicAdd(&stats[which * 256 + colbase + c], s);
        }
    }
}

// ---------------------------------------------------------------- pooling
__global__ void graph_bounds(const int* __restrict__ batch, int* __restrict__ gstart, int N) {
    int t = threadIdx.x;
    if (t > NGRAPH) return;
    if (t == NGRAPH) { gstart[t] = N; return; }
    int lo = 0, hi = N;
    while (lo < hi) { int m = (lo + hi) >> 1; if (batch[m] < t) lo = m + 1; else hi = m; }
    gstart[t] = lo;
}

// stage1: 256-node chunks, 512 threads (16 row-lanes x 32 col-chunks of 8),
// BN affine + ReLU fused; LDS reduce across row-lanes; atomicAdd per segment.
#define PCHUNK 256
__global__ void pool_stage1(const _Float16* __restrict__ z, const int* __restrict__ batch,
                            const int* __restrict__ gstart, const float* __restrict__ stats,
                            const float* __restrict__ gam, const float* __restrict__ bet,
                            float* __restrict__ acc, int N, float invN) {
    __shared__ float lds[8 * 512];
    int c0 = blockIdx.x * PCHUNK;
    int cend = min(c0 + PCHUNK, N);
    int tid = threadIdx.x;
    int rowlane = tid >> 5;
    int fb = (tid & 31) << 3;
    float sc[8], tc[8];
#pragma unroll
    for (int k = 0; k < 8; ++k) {
        float mu = stats[fb + k] * invN;
        float var = stats[256 + fb + k] * invN - mu * mu;
        float s = gam[fb + k] * rsqrtf(var + BN_EPS);
        sc[k] = s;
        tc[k] = bet[fb + k] - mu * s;
    }
    int segs = c0;
    while (segs < cend) {
        int g = batch[segs];
        int sege = min(gstart[g + 1], cend);
        float a[8] = {0.f, 0.f, 0.f, 0.f, 0.f, 0.f, 0.f, 0.f};
        for (int r = segs + rowlane; r < sege; r += 16) {
            half8 v = *(const half8*)(z + (size_t)r * 256 + fb);
#pragma unroll
            for (int k = 0; k < 8; ++k)
                a[k] += fmaxf(fmaf((float)v[k], sc[k], tc[k]), 0.f);
        }
#pragma unroll
        for (int k = 0; k < 8; ++k) lds[k * 512 + tid] = a[k];
        __syncthreads();
#pragma unroll
        for (int d = 8; d > 0; d >>= 1) {
            if (rowlane < d) {
#pragma unroll
                for (int k = 0; k < 8; ++k)
                    lds[k * 512 + tid] += lds[k * 512 + tid + d * 32];
            }
            __syncthreads();
        }
        if (rowlane == 0) {
#pragma unroll
            for (int k = 0; k < 8; ++k)
                atomicAdd(&acc[g * 256 + fb + k], lds[k * 512 + tid]);
        }
        __syncthreads();
        segs = sege;
    }
}

__global__ void pool_finalize(const float* __restrict__ acc, const int* __restrict__ gstart,
                              float* __restrict__ out) {
    int i = blockIdx.x * 256 + threadIdx.x;
    int g = i >> 8;
    int c = gstart[g + 1] - gstart[g];
    out[i] = acc[i] / (float)(c > 0 ? c : 1);
}

// ---------------------------------------------------------------- launch
extern "C" void kernel_launch(void* const* d_in, const int* in_sizes, int n_in,
                              void* d_out, int out_size, void* d_ws, size_t ws_size,
                              hipStream_t stream) {
    const float* x    = (const float*)d_in[0];
    const int*   ei   = (const int*)d_in[1];
    const int*   batch= (const int*)d_in[2];
    const float* w1_0 = (const float*)d_in[3];
    const float* b1_0 = (const float*)d_in[4];
    const float* w2_0 = (const float*)d_in[5];
    const float* b2_0 = (const float*)d_in[6];
    const float* g_0  = (const float*)d_in[7];
    const float* be_0 = (const float*)d_in[8];
    const float* w1_r = (const float*)d_in[9];
    const float* b1_r = (const float*)d_in[10];
    const float* w2_r = (const float*)d_in[11];
    const float* b2_r = (const float*)d_in[12];
    const float* g_r  = (const float*)d_in[13];
    const float* be_r = (const float*)d_in[14];

    const int N = in_sizes[0] / 128;   // 50000
    const int E = in_sizes[1] / 2;     // 800000

    // workspace carve (256B aligned)
    char* p = (char*)d_ws;
    auto alloc = [&](size_t bytes) { char* r = p; p += (bytes + 255) & ~(size_t)255; return r; };
    float*    stats   = (float*)alloc(4 * 512 * sizeof(float));
    int*      part    = (int*)alloc(256 * sizeof(int));
    int*      off     = (int*)alloc((size_t)(N + 1) * sizeof(int));
    int*      cnt     = (int*)alloc((size_t)N * sizeof(int));
    int*      gstart  = (int*)alloc(65 * sizeof(int));
    float*    acc     = (float*)alloc(NGRAPH * 256 * sizeof(float));
    int*      rank    = (int*)alloc((size_t)E * sizeof(int));
    int*      csr_src = (int*)alloc((size_t)E * sizeof(int));
    _Float16* wT      = (_Float16*)alloc((size_t)491520 * sizeof(_Float16));
    _Float16* zin     = (_Float16*)alloc((size_t)N * 256 * sizeof(_Float16));
    _Float16* y       = (_Float16*)alloc((size_t)N * 256 * sizeof(_Float16));
    _Float16* z       = (_Float16*)alloc((size_t)N * 256 * sizeof(_Float16));

    hipMemsetAsync(stats, 0, 4 * 512 * sizeof(float), stream);
    hipMemsetAsync(cnt, 0, (size_t)N * sizeof(int), stream);
    hipMemsetAsync(acc, 0, NGRAPH * 256 * sizeof(float), stream);

    // transpose all weights to fp16 [256][K]
    PrepArgs pa;
    pa.src[0] = w1_0;  pa.dst[0] = wT;           pa.K[0] = 128;
    pa.src[1] = w2_0;  pa.dst[1] = wT + 32768;   pa.K[1] = 256;
    for (int i = 0; i < 3; ++i) {
        pa.src[2 + i] = w1_r + (size_t)i * 65536; pa.dst[2 + i] = wT + 98304 + (size_t)i * 65536; pa.K[2 + i] = 256;
        pa.src[5 + i] = w2_r + (size_t)i * 65536; pa.dst[5 + i] = wT + 294912 + (size_t)i * 65536; pa.K[5 + i] = 256;
    }
    prep_weights<<<dim3(256, 8), 256, 0, stream>>>(pa);

    const int eb = (E + 255) / 256;
    const int nb = (N + 255) / 256;
    edge_count<<<eb, 256, 0, stream>>>(ei, cnt, rank, E);
    scan_p1<<<nb, 256, 0, stream>>>(cnt, part, N);
    scan_p2<<<1, 256, 0, stream>>>(part, off, N, nb);
    scan_p3<<<nb, 256, 0, stream>>>(cnt, part, off, N);
    edge_fill<<<eb, 256, 0, stream>>>(ei, off, rank, csr_src, E);
    graph_bounds<<<1, 128, 0, stream>>>(batch, gstart, N);

    const int gwb   = (N + 3) / 4;               // gather blocks (4 waves each)
    const dim3 gemmg((N + 127) / 128, 2);
    const float invN = 1.0f / (float)N;

    // ---- layer 0 (K=128 input, no norm on input)
    gather_f32<<<gwb, 256, 0, stream>>>(x, off, csr_src, zin, N);
    gemm_kernel<128, 0><<<gemmg, 512, 128 * 128 * 2, stream>>>(zin, wT, b1_0, y, nullptr, nullptr, N);
    gemm_kernel<256, 1><<<gemmg, 512, 128 * 256 * 2, stream>>>(y, wT + 32768, b2_0, nullptr, z, stats, N);

    // ---- layers 1..3 (BN of previous layer fused into gather)
    const float* cur_stats = stats;
    const float* cur_g = g_0;
    const float* cur_be = be_0;
    for (int i = 0; i < 3; ++i) {
        gather_fused<<<gwb, 256, 0, stream>>>(z, off, csr_src, cur_stats, cur_g, cur_be, zin, N, invN);
        gemm_kernel<256, 0><<<gemmg, 512, 128 * 256 * 2, stream>>>(
            zin, wT + 98304 + (size_t)i * 65536, b1_r + i * 256, y, nullptr, nullptr, N);
        gemm_kernel<256, 1><<<gemmg, 512, 128 * 256 * 2, stream>>>(
            y, wT + 294912 + (size_t)i * 65536, b2_r + i * 256, nullptr, z, stats + (i + 1) * 512, N);
        cur_stats = stats + (i + 1) * 512;
        cur_g = g_r + i * 256;
        cur_be = be_r + i * 256;
    }

    // ---- pool (BN of last layer fused)
    pool_stage1<<<(N + PCHUNK - 1) / PCHUNK, 512, 0, stream>>>(
        z, batch, gstart, cur_stats, cur_g, cur_be, acc, N, invN);
    pool_finalize<<<NGRAPH, 256, 0, stream>>>(acc, gstart, (float*)d_out);
}